// Round 2
// baseline (239.268 us; speedup 1.0000x reference)
//
#include <hip/hip_runtime.h>
#include <math.h>

// Problem constants (fixed by setup_inputs): B=512, C=3000, T=25.
#define B_ 512
#define C_ 3000
#define T_ 25
#define C4_ (C_ / 4)            // 750 float4 per row
#define TG_ 5                   // t-groups (grid.y)
#define NT_ 5                   // noise draws per group (TG_*NT_ == T_)

typedef float v4f __attribute__((ext_vector_type(4)));

// R7: occupancy fix. Profile showed the 228 µs headline is ~180 µs of harness
// re-poison fills (6.8 TB/s, can't touch) + ~48 µs of ace_rows at ~3.4 TB/s.
// ace_rows was grid-limited: 512 blocks = 2 blocks/CU = 8 waves/CU (25% occ),
// latency-bound on the noise stream. Split the 25 draws across 5 blocks per
// row: grid 512x5 -> ~10 blocks/CU available, 32 waves/CU resident. S/D
// shrink 26->6 entries so VGPR fits the 128 cap (launch_bounds 256,4).
// pred/true re-read x5 (+49 MB) is LLC-resident; HBM bytes stay ~166 MB.
__global__ __launch_bounds__(256, 4) void ace_rows(
    const float* __restrict__ logit_var,   // [B,1]
    const float* __restrict__ pred,        // [B,C]
    const float* __restrict__ tru,         // [B,C]
    const float* __restrict__ noise,       // [T,B,C]
    float* __restrict__ dsum)              // [T+1] per-t sum over b of row loss
{
    const int tid = threadIdx.x;
    const int b   = blockIdx.x;
    const int tg  = blockIdx.y;            // which group of NT_ draws
    const bool un = (tg == 0);             // group 0 also does undistorted row

    const float4* __restrict__ p4 = (const float4*)(pred + (size_t)b * C_);
    const float4* __restrict__ t4 = (const float4*)(tru  + (size_t)b * C_);

    const int  i0   = tid;
    const int  i1   = tid + 256;
    const bool has2 = (tid < C4_ - 512);        // tid < 238
    const int  i2   = has2 ? tid + 512 : tid;   // clamped (safe) address

    const float stdv = sqrtf(logit_var[b]);

    float4 pv0 = p4[i0], pv1 = p4[i1], pv2 = p4[i2];
    float4 tv0 = t4[i0], tv1 = t4[i1], tv2 = t4[i2];

    float p[12], tr[12];
    p[0]=pv0.x; p[1]=pv0.y; p[2]=pv0.z; p[3]=pv0.w;
    p[4]=pv1.x; p[5]=pv1.y; p[6]=pv1.z; p[7]=pv1.w;
    p[8]=pv2.x; p[9]=pv2.y; p[10]=pv2.z; p[11]=pv2.w;
    tr[0]=tv0.x; tr[1]=tv0.y; tr[2]=tv0.z; tr[3]=tv0.w;
    tr[4]=tv1.x; tr[5]=tv1.y; tr[6]=tv1.z; tr[7]=tv1.w;
    tr[8]=tv2.x; tr[9]=tv2.y; tr[10]=tv2.z; tr[11]=tv2.w;
    if (!has2) {
        // poison tail lanes: exp(-1e30)=0, tr=0 kills dot/Tm contributions.
#pragma unroll
        for (int j = 8; j < 12; ++j) { p[j] = -1e30f; tr[j] = 0.f; }
    }

    // Slots 0..NT_-1: this group's draws. Slot NT_: undistorted (tg 0 only).
    float S[NT_ + 1], D[NT_ + 1];
    float Tm = 0.f;
#pragma unroll
    for (int j = 0; j < 12; ++j) Tm += tr[j];

    S[NT_] = 0.f; D[NT_] = 0.f;
    if (un) {
        float s_acc = 0.f, d_acc = 0.f;
#pragma unroll
        for (int j = 0; j < 12; ++j) {
            s_acc += __expf(p[j]);
            d_acc  = fmaf(p[j], tr[j], d_acc);
        }
        S[NT_] = s_acc; D[NT_] = d_acc;
    }

    const v4f* __restrict__ nb = (const v4f*)(noise + (size_t)b * C_);
#pragma unroll
    for (int s = 0; s < NT_; ++s) {
        const int t = tg * NT_ + s;
        const v4f* __restrict__ n4 = nb + (size_t)t * (size_t)(B_ * C4_);
        // read-once stream: nontemporal (no L2 allocation / eviction work)
        v4f nv0 = __builtin_nontemporal_load(n4 + i0);
        v4f nv1 = __builtin_nontemporal_load(n4 + i1);
        v4f nv2 = __builtin_nontemporal_load(n4 + i2);
        float n[12];
        n[0]=nv0.x; n[1]=nv0.y; n[2]=nv0.z; n[3]=nv0.w;
        n[4]=nv1.x; n[5]=nv1.y; n[6]=nv1.z; n[7]=nv1.w;
        n[8]=nv2.x; n[9]=nv2.y; n[10]=nv2.z; n[11]=nv2.w;
        float s_acc = 0.f, d_acc = 0.f;
#pragma unroll
        for (int j = 0; j < 12; ++j) {
            float x = fmaf(stdv, n[j], p[j]);   // tail lanes: -1e30 -> exp 0
            s_acc += __expf(x);
            d_acc  = fmaf(x, tr[j], d_acc);
        }
        S[s] = s_acc; D[s] = d_acc;
    }

    // 64-lane butterfly reduction of Tm and the 6 (S,D) pairs.
    for (int off = 32; off > 0; off >>= 1) {
        Tm += __shfl_xor(Tm, off);
#pragma unroll
        for (int s = 0; s <= NT_; ++s) {
            S[s] += __shfl_xor(S[s], off);
            D[s] += __shfl_xor(D[s], off);
        }
    }

    // Cross-wave combine via LDS; threads 0..NT_ finish their slot.
    __shared__ float redS[NT_ + 1][4], redD[NT_ + 1][4], redTm[4];
    const int wave = tid >> 6, lane = tid & 63;
    if (lane == 0) {
        redTm[wave] = Tm;
#pragma unroll
        for (int s = 0; s <= NT_; ++s) { redS[s][wave] = S[s]; redD[s][wave] = D[s]; }
    }
    __syncthreads();
    if (tid <= NT_) {
        const bool is_un = (tid == NT_);
        if (!is_un || un) {
            float Sa  = redS[tid][0] + redS[tid][1] + redS[tid][2] + redS[tid][3];
            float Da  = redD[tid][0] + redD[tid][1] + redD[tid][2] + redD[tid][3];
            float Tma = redTm[0] + redTm[1] + redTm[2] + redTm[3];
            float lse = logf(Sa);                    // no max shift needed
            const int slot = is_un ? T_ : (tg * NT_ + tid);
            atomicAdd(&dsum[slot], (lse * Tma - Da) * 0.1f);
        }
    }
}

// Single wave: depressor reduction over B=512, per-t means, elu, final 4 outputs.
__global__ __launch_bounds__(64) void ace_final(
    const float* __restrict__ logit_var,
    const float* __restrict__ dsum,
    float* __restrict__ out)
{
    const int lane = threadIdx.x;

    float dep = 0.0f;
    for (int i = lane; i < B_; i += 64)
        dep += __expf(logit_var[i]) - 1.0f;

    const float undist = dsum[T_] * (1.0f / B_);
    float d  = (lane < T_) ? dsum[lane] * (1.0f / B_) : 0.0f;
    float el = 0.0f;
    if (lane < T_) {
        float x   = undist - d;
        float elu = (x > 0.0f) ? x : (__expf(x) - 1.0f);
        el = -elu;
    }

    for (int off = 32; off > 0; off >>= 1) {
        dep += __shfl_xor(dep, off);
        d   += __shfl_xor(d, off);
        el  += __shfl_xor(el, off);
    }

    if (lane == 0) {
        out[0] = d  * (1.0f / T_);   // gce_loss
        out[1] = el * (1.0f / T_);   // variance_loss
        out[2] = undist;             // undistorted_loss
        out[3] = dep * (1.0f / B_);  // variance_depressor
    }
}

extern "C" void kernel_launch(void* const* d_in, const int* in_sizes, int n_in,
                              void* d_out, int out_size, void* d_ws, size_t ws_size,
                              hipStream_t stream) {
    const float* logit_var = (const float*)d_in[0];  // [512,1]
    const float* pred      = (const float*)d_in[1];  // [512,3000]
    const float* tru       = (const float*)d_in[2];  // [512,3000]
    const float* noise     = (const float*)d_in[3];  // [25,512,3000]
    float* out  = (float*)d_out;                     // 4 fp32 scalars
    float* dsum = (float*)d_ws;                      // (T+1) fp32 accumulators

    hipMemsetAsync(dsum, 0, (T_ + 1) * sizeof(float), stream);
    ace_rows<<<dim3(B_, TG_), 256, 0, stream>>>(logit_var, pred, tru, noise, dsum);
    ace_final<<<1, 64, 0, stream>>>(logit_var, dsum, out);
}